// Round 8
// baseline (2388.256 us; speedup 1.0000x reference)
//
#include <hip/hip_runtime.h>
#include <hip/hip_bf16.h>
#include <math.h>

// Shapes
#define N_TRAIN 4096
#define N_FEAT  64
#define N_HID   256
#define ENC     256
#define N_ANTES 2048
#define ATT_H   256
#define MAX_LEN 16

typedef unsigned int u32;

__device__ __forceinline__ float fsig(float x)  { return 1.f / (1.f + __expf(-x)); }
__device__ __forceinline__ float ftanh(float x) { return 2.f / (1.f + __expf(-2.f * x)) - 1.f; }

// ---------------------------------------------------------------------------
// Tiled GEMM: C[m,n] = act(bias[n] + sum_k A[m,k] * B[n,k]); 64x64x16 tiles.
// ---------------------------------------------------------------------------
template <bool RELU>
__global__ __launch_bounds__(256) void gemm_abT(
    const float* __restrict__ A, const float* __restrict__ B,
    const float* __restrict__ bias, float* __restrict__ C,
    int M, int N, int K, int lda, int ldb, int ldc)
{
    __shared__ __align__(16) float As[16][68];
    __shared__ __align__(16) float Bs[16][68];
    const int tid = threadIdx.x;
    const int m0 = blockIdx.x * 64, n0 = blockIdx.y * 64;
    const int tx = tid & 15, ty = tid >> 4;
    const int kl = tid & 15, rl = tid >> 4;
    float acc[4][4] = {};

    for (int k0 = 0; k0 < K; k0 += 16) {
        #pragma unroll
        for (int pp = 0; pp < 4; ++pp) {
            int r = rl + pp * 16;
            As[kl][r] = A[(size_t)(m0 + r) * lda + k0 + kl];
            Bs[kl][r] = B[(size_t)(n0 + r) * ldb + k0 + kl];
        }
        __syncthreads();
        #pragma unroll
        for (int k = 0; k < 16; ++k) {
            float4 av = *(const float4*)&As[k][ty * 4];
            float4 bv = *(const float4*)&Bs[k][tx * 4];
            float a4[4] = {av.x, av.y, av.z, av.w};
            float b4[4] = {bv.x, bv.y, bv.z, bv.w};
            #pragma unroll
            for (int i = 0; i < 4; ++i)
                #pragma unroll
                for (int j = 0; j < 4; ++j)
                    acc[i][j] = fmaf(a4[i], b4[j], acc[i][j]);
        }
        __syncthreads();
    }
    #pragma unroll
    for (int i = 0; i < 4; ++i) {
        int m = m0 + ty * 4 + i;
        #pragma unroll
        for (int j = 0; j < 4; ++j) {
            int n = n0 + tx * 4 + j;
            float v = acc[i][j] + bias[n];
            if (RELU) v = fmaxf(v, 0.f);
            C[(size_t)m * ldc + n] = v;
        }
    }
}

// ---------------------------------------------------------------------------
// Split-K GEMM, KSPLIT=4, partials to plain buffers (no atomics).
// Grid (M/64, N/64, 4). float4 staging, register double-buffer, conflict-free.
// ---------------------------------------------------------------------------
#define KSPLIT 4
__global__ __launch_bounds__(256) void gemm_ab_splitk(
    const float* __restrict__ A, const float* __restrict__ B,
    float* __restrict__ pA, float* __restrict__ pB,
    int M, int N, int K, int lda, int ldb, int ldc)
{
    __shared__ __align__(16) float As[16][68];
    __shared__ __align__(16) float Bs[16][68];
    const int tid = threadIdx.x;
    const int m0 = blockIdx.x * 64, n0 = blockIdx.y * 64;
    const int kchunk = K / KSPLIT;
    const int kbeg = blockIdx.z * kchunk, kend = kbeg + kchunk;
    const int tx = tid & 15, ty = tid >> 4;
    const int arow = tid & 63, akq = tid >> 6;   // A: 64 rows x 4 k-quads
    const int bnq = tid & 15, bkk = tid >> 4;    // B: 16 n-quads x 16 k
    float acc[4][4] = {};

    float4 avn = *(const float4*)&A[(size_t)(m0 + arow) * lda + kbeg + akq * 4];
    float4 bvn = *(const float4*)&B[(size_t)(kbeg + bkk) * ldb + n0 + bnq * 4];

    for (int k0 = kbeg; k0 < kend; k0 += 16) {
        float4 av = avn, bv = bvn;
        if (k0 + 16 < kend) {
            avn = *(const float4*)&A[(size_t)(m0 + arow) * lda + k0 + 16 + akq * 4];
            bvn = *(const float4*)&B[(size_t)(k0 + 16 + bkk) * ldb + n0 + bnq * 4];
        }
        __syncthreads();             // prev iter's compute done -> LDS free
        As[akq * 4 + 0][arow] = av.x;
        As[akq * 4 + 1][arow] = av.y;
        As[akq * 4 + 2][arow] = av.z;
        As[akq * 4 + 3][arow] = av.w;
        *(float4*)&Bs[bkk][bnq * 4] = bv;
        __syncthreads();
        #pragma unroll
        for (int k = 0; k < 16; ++k) {
            float4 a4v = *(const float4*)&As[k][ty * 4];
            float4 b4v = *(const float4*)&Bs[k][tx * 4];
            float a4[4] = {a4v.x, a4v.y, a4v.z, a4v.w};
            float b4[4] = {b4v.x, b4v.y, b4v.z, b4v.w};
            #pragma unroll
            for (int i = 0; i < 4; ++i)
                #pragma unroll
                for (int j = 0; j < 4; ++j)
                    acc[i][j] = fmaf(a4[i], b4[j], acc[i][j]);
        }
    }
    float* Cp = (blockIdx.z < 2) ? (pA + (size_t)blockIdx.z * (ATT_H * N_ANTES))
                                 : (pB + (size_t)(blockIdx.z - 2) * (ATT_H * N_ANTES));
    #pragma unroll
    for (int i = 0; i < 4; ++i)
        #pragma unroll
        for (int j = 0; j < 4; ++j)
            Cp[(size_t)(m0 + ty * 4 + i) * ldc + n0 + tx * 4 + j] = acc[i][j];
}

__global__ __launch_bounds__(256) void k_reduce(
    const float* __restrict__ pA, const float* __restrict__ pB,
    float* __restrict__ preT)
{
    int gid = blockIdx.x * 256 + threadIdx.x;
    const int SZ = ATT_H * N_ANTES;
    preT[gid] = (pA[gid] + pA[gid + SZ]) + (pB[gid] + pB[gid + SZ]);
}

// ---------------------------------------------------------------------------
// rowsum[j] = sum_k w_ih[j, k]
// ---------------------------------------------------------------------------
__global__ __launch_bounds__(256) void k_rowsum(const float* __restrict__ w_ih,
                                                float* __restrict__ rowsum)
{
    __shared__ float red[256];
    const int j = blockIdx.x, tid = threadIdx.x;
    float s = 0.f;
    for (int i = tid; i < N_ANTES; i += 256) s += w_ih[(size_t)j * N_ANTES + i];
    red[tid] = s; __syncthreads();
    for (int off = 128; off > 0; off >>= 1) {
        if (tid < off) red[tid] += red[tid + off];
        __syncthreads();
    }
    if (tid == 0) rowsum[j] = red[0];
}

// ---------------------------------------------------------------------------
// wpkT[k*1024 + j] = w_hh[j*256 + k]
// ---------------------------------------------------------------------------
__global__ __launch_bounds__(256) void k_packT(const float* __restrict__ w_hh,
                                               float* __restrict__ wpkT)
{
    int gid = blockIdx.x * 256 + threadIdx.x;
    int j = gid >> 8;
    int k = gid & 255;
    wpkT[(size_t)k * 1024 + j] = w_hh[gid];
}

// ---------------------------------------------------------------------------
// WbT[k*256 + j] = att_w1[j*(N_TRAIN+ENC) + N_TRAIN + k]
// ---------------------------------------------------------------------------
__global__ __launch_bounds__(256) void k_wbT(const float* __restrict__ att_w1,
                                             float* __restrict__ WbT)
{
    int gid = blockIdx.x * 256 + threadIdx.x;
    int j = gid >> 8, k = gid & 255;
    WbT[(size_t)k * 256 + j] = att_w1[(size_t)j * (N_TRAIN + ENC) + N_TRAIN + k];
}

// ---------------------------------------------------------------------------
// Fused LSTM step + attention + softmax: ONE kernel per step.
// Grid 256 x 1024. Main path = R5's proven k_lstm (4-deep register prefetch,
// no barrier in the K-loop). The last block to finish (device-scope ticket)
// computes u, all 2048 scores, log-softmax + argmax, writes out_t and idx.
// ---------------------------------------------------------------------------
#define LROWS 16
#define HSTR 20
__global__ __launch_bounds__(1024, 4) void k_lstm_att(
    float* __restrict__ h, float* __restrict__ c,
    const float* __restrict__ wpkT, const float* __restrict__ rowsum,
    const float* __restrict__ b_ih, const float* __restrict__ b_hh,
    const float* __restrict__ S, int* __restrict__ idx_buf, int t,
    float* __restrict__ e_acc_t, const float* __restrict__ preT,
    const float* __restrict__ WbT, const float* __restrict__ att_b1,
    const float* __restrict__ att_w2, const float* __restrict__ att_b2,
    float* __restrict__ out_t, u32* __restrict__ counter)
{
    __shared__ __align__(16) float h_lds[256 * HSTR];   // [k][r], 20 KB
    __shared__ float z_lds[LROWS * 1024];               // [r][j], 64 KB
    __shared__ float red[1024];
    __shared__ float a_lds[LROWS];
    __shared__ float e_lds[256];
    __shared__ float u_lds[256];
    __shared__ float w2_lds[256];
    __shared__ u32 done;
    int* ridx = (int*)z_lds;                            // reuse in tail phase

    const int tid = threadIdx.x;
    const int n0 = blockIdx.x * LROWS;
    const int jj = tid & 255, rq = tid >> 8;

    // ---- phase 1: rank-1 x column ----
    if (tid < LROWS) {
        float a = 1.0f;
        if (t > 0) a = S[(size_t)(n0 + tid) * N_ANTES + idx_buf[t - 1]];
        a_lds[tid] = a;
    }
    // stage h tile -> h_lds[k][r], spread over all 1024 threads
    #pragma unroll
    for (int i = 0; i < 4; ++i) {
        int r = rq * 4 + i;
        h_lds[jj * HSTR + r] = h[(size_t)(n0 + r) * 256 + jj];
    }

    // 4-deep rotating register prefetch (wpkT padded +4 k-rows)
    float wbuf[4];
    #pragma unroll
    for (int i = 0; i < 4; ++i) wbuf[i] = wpkT[(size_t)i * 1024 + tid];

    const float rs = rowsum[tid];
    const float bs = b_ih[tid] + b_hh[tid];
    __syncthreads();

    // ---- phase 2: z = a*rowsum + bias + h @ w_hh^T ----
    float acc[LROWS];
    #pragma unroll
    for (int r = 0; r < LROWS; ++r) acc[r] = fmaf(a_lds[r], rs, bs);

    for (int k4 = 0; k4 < 256; k4 += 4) {
        #pragma unroll
        for (int u = 0; u < 4; ++u) {
            float w = wbuf[u];
            wbuf[u] = wpkT[(size_t)(k4 + 4 + u) * 1024 + tid];  // pad rows ok
            const float4* hrow = (const float4*)&h_lds[(k4 + u) * HSTR];
            float4 h0v = hrow[0], h1v = hrow[1], h2v = hrow[2], h3v = hrow[3];
            float hk[LROWS] = {h0v.x, h0v.y, h0v.z, h0v.w,
                               h1v.x, h1v.y, h1v.z, h1v.w,
                               h2v.x, h2v.y, h2v.z, h2v.w,
                               h3v.x, h3v.y, h3v.z, h3v.w};
            #pragma unroll
            for (int r = 0; r < LROWS; ++r)
                acc[r] = fmaf(w, hk[r], acc[r]);
        }
    }

    // ---- phase 3: gate exchange + fused c/h update + e partial ----
    #pragma unroll
    for (int r = 0; r < LROWS; ++r) z_lds[r * 1024 + tid] = acc[r];
    __syncthreads();
    float esum = 0.f;
    #pragma unroll
    for (int i = 0; i < 4; ++i) {
        int r = rq * 4 + i;
        float zi = z_lds[r * 1024 + jj];
        float zf = z_lds[r * 1024 + 256 + jj];
        float zg = z_lds[r * 1024 + 512 + jj];
        float zo = z_lds[r * 1024 + 768 + jj];
        size_t off = (size_t)(n0 + r) * 256 + jj;
        float cn = fsig(zf) * c[off] + fsig(zi) * ftanh(zg);
        float hn = fsig(zo) * ftanh(cn);
        c[off] = cn;
        h[off] = hn;
        esum += hn;
    }
    red[tid] = esum;
    __syncthreads();
    if (tid < 256) {
        float e = (red[tid] + red[tid + 256]) + (red[tid + 512] + red[tid + 768]);
        atomicAdd(&e_acc_t[tid], e);
    }

    // ---- ticket: last block does attention + softmax ----
    __threadfence();
    __syncthreads();
    if (tid == 0) done = atomicAdd(counter, 1u);
    __syncthreads();
    if (done != 255) return;
    __threadfence();

    if (tid < 256) {
        e_lds[tid] = __hip_atomic_load(&e_acc_t[tid], __ATOMIC_RELAXED,
                                       __HIP_MEMORY_SCOPE_AGENT) * (1.f / (float)N_TRAIN);
        w2_lds[tid] = att_w2[tid];
    }
    __syncthreads();

    // u[j] = att_b1[j] + e . WbT[:,j]  (4-way k-split over the block)
    {
        float ua = 0.f;
        for (int k = rq * 64; k < rq * 64 + 64; ++k)
            ua = fmaf(e_lds[k], WbT[(size_t)k * 256 + jj], ua);
        red[tid] = ua;
        __syncthreads();
        if (tid < 256)
            u_lds[tid] = att_b1[tid] +
                ((red[tid] + red[tid + 256]) + (red[tid + 512] + red[tid + 768]));
    }
    __syncthreads();

    // scores: thread owns columns p0=tid, p1=tid+1024 (coalesced preT rows)
    const float ab2 = att_b2[0];
    float sc0 = ab2, sc1 = ab2;
    for (int j = 0; j < 256; ++j) {
        float uj = u_lds[j], wj = w2_lds[j];
        float v0 = preT[(size_t)j * N_ANTES + tid] + uj;
        float v1 = preT[(size_t)j * N_ANTES + tid + 1024] + uj;
        sc0 = fmaf(fmaxf(v0, 0.f), wj, sc0);
        sc1 = fmaf(fmaxf(v1, 0.f), wj, sc1);
    }

    // argmax (ties -> smaller index) + log-softmax over 2048
    float lmax; int lidx;
    if (sc1 > sc0) { lmax = sc1; lidx = tid + 1024; }
    else           { lmax = sc0; lidx = tid; }
    red[tid] = lmax; ridx[tid] = lidx;
    __syncthreads();
    for (int off = 512; off > 0; off >>= 1) {
        if (tid < off) {
            float ov = red[tid + off]; int oi = ridx[tid + off];
            if (ov > red[tid] || (ov == red[tid] && oi < ridx[tid])) {
                red[tid] = ov; ridx[tid] = oi;
            }
        }
        __syncthreads();
    }
    const float gmax = red[0];
    const int gidx = ridx[0];
    __syncthreads();

    red[tid] = __expf(sc0 - gmax) + __expf(sc1 - gmax);
    __syncthreads();
    for (int off = 512; off > 0; off >>= 1) {
        if (tid < off) red[tid] += red[tid + off];
        __syncthreads();
    }
    const float lse = gmax + logf(red[0]);

    out_t[tid]        = sc0 - lse;
    out_t[tid + 1024] = sc1 - lse;
    if (tid == 0) idx_buf[t] = gidx;
}

// ---------------------------------------------------------------------------
extern "C" void kernel_launch(void* const* d_in, const int* in_sizes, int n_in,
                              void* d_out, int out_size, void* d_ws, size_t ws_size,
                              hipStream_t stream)
{
    (void)in_sizes; (void)n_in; (void)out_size; (void)ws_size;
    const float* context = (const float*)d_in[0];
    const float* S       = (const float*)d_in[1];
    const float* enc_w1  = (const float*)d_in[2];
    const float* enc_b1  = (const float*)d_in[3];
    const float* enc_w2  = (const float*)d_in[4];
    const float* enc_b2  = (const float*)d_in[5];
    const float* w_ih    = (const float*)d_in[6];
    const float* w_hh    = (const float*)d_in[7];
    const float* b_ih    = (const float*)d_in[8];
    const float* b_hh    = (const float*)d_in[9];
    const float* att_w1  = (const float*)d_in[10];
    const float* att_b1  = (const float*)d_in[11];
    const float* att_w2  = (const float*)d_in[12];
    const float* att_b2  = (const float*)d_in[13];
    float* out = (float*)d_out;
    float* ws  = (float*)d_ws;

    // ws layout (float offsets)
    float* h      = ws;                        // 1,048,576
    float* c      = ws + 1048576;              // 1,048,576
    float* pAbuf  = ws + 2097152;              // 1,048,576 (hid1 aliases slice 0)
    float* preT   = ws + 3145728;              // 524,288 (j-major [j][p])
    float* pBbuf  = ws + 3670016;              // 1,048,576
    float* wpkT   = ws + 4718592;              // (256+4)*1024 = 266,240
    float* rowsum = ws + 4984832;              // 1,024
    float* e_acc  = ws + 4985856;              // 4,096
    u32*   cnt    = (u32*)(ws + 4989952);      // 16
    int*   idxbuf = (int*)(ws + 4989968);      // 16
    float* WbT    = ws + 4990000;              // 65,536 (starts 16B-aligned)

    hipMemsetAsync(c, 0, (size_t)N_TRAIN * ENC * sizeof(float), stream);
    // e_acc (16x256 floats) + cnt (16 u32) contiguous -> one memset
    hipMemsetAsync(e_acc, 0, (size_t)MAX_LEN * ENC * sizeof(float) + 16 * sizeof(u32), stream);

    k_rowsum<<<1024, 256, 0, stream>>>(w_ih, rowsum);
    k_packT<<<1024, 256, 0, stream>>>(w_hh, wpkT);
    k_wbT<<<256, 256, 0, stream>>>(att_w1, WbT);

    // encoder: hid1 = relu(context @ enc_w1.T + b1); h = hid1 @ enc_w2.T + b2
    float* hid1 = pAbuf;
    dim3 g1(N_TRAIN / 64, N_HID / 64);
    gemm_abT<true><<<g1, 256, 0, stream>>>(context, enc_w1, enc_b1, hid1,
                                           N_TRAIN, N_HID, N_FEAT, N_FEAT, N_FEAT, N_HID);
    dim3 g2(N_TRAIN / 64, ENC / 64);
    gemm_abT<false><<<g2, 256, 0, stream>>>(hid1, enc_w2, enc_b2, h,
                                            N_TRAIN, ENC, N_HID, N_HID, N_HID, ENC);
    // preT = Wa @ S via split-K=4 partials (pAbuf reused after gemm #2)
    dim3 g3(ATT_H / 64, N_ANTES / 64, KSPLIT);
    gemm_ab_splitk<<<g3, 256, 0, stream>>>(att_w1, S, pAbuf, pBbuf,
                                           ATT_H, N_ANTES, N_TRAIN,
                                           N_TRAIN + ENC, N_ANTES, N_ANTES);
    k_reduce<<<(ATT_H * N_ANTES) / 256, 256, 0, stream>>>(pAbuf, pBbuf, preT);

    for (int t = 0; t < MAX_LEN; ++t) {
        k_lstm_att<<<N_TRAIN / LROWS, 1024, 0, stream>>>(
            h, c, wpkT, rowsum, b_ih, b_hh, S, idxbuf, t, e_acc + t * 256,
            preT, WbT, att_b1, att_w2, att_b2, out + t * N_ANTES, cnt + t);
    }
}

// Round 9
// 1086.995 us; speedup vs baseline: 2.1971x; 2.1971x over previous
//
#include <hip/hip_runtime.h>
#include <hip/hip_bf16.h>
#include <math.h>

// Shapes
#define N_TRAIN 4096
#define N_FEAT  64
#define N_HID   256
#define ENC     256
#define N_ANTES 2048
#define ATT_H   256
#define MAX_LEN 16

typedef unsigned int u32;

__device__ __forceinline__ float fsig(float x)  { return 1.f / (1.f + __expf(-x)); }
__device__ __forceinline__ float ftanh(float x) { return 2.f / (1.f + __expf(-2.f * x)) - 1.f; }

// ---------------------------------------------------------------------------
// Tiled GEMM: C[m,n] = act(bias[n] + sum_k A[m,k] * B[n,k]); 64x64x16 tiles.
// ---------------------------------------------------------------------------
template <bool RELU>
__global__ __launch_bounds__(256) void gemm_abT(
    const float* __restrict__ A, const float* __restrict__ B,
    const float* __restrict__ bias, float* __restrict__ C,
    int M, int N, int K, int lda, int ldb, int ldc)
{
    __shared__ __align__(16) float As[16][68];
    __shared__ __align__(16) float Bs[16][68];
    const int tid = threadIdx.x;
    const int m0 = blockIdx.x * 64, n0 = blockIdx.y * 64;
    const int tx = tid & 15, ty = tid >> 4;
    const int kl = tid & 15, rl = tid >> 4;
    float acc[4][4] = {};

    for (int k0 = 0; k0 < K; k0 += 16) {
        #pragma unroll
        for (int pp = 0; pp < 4; ++pp) {
            int r = rl + pp * 16;
            As[kl][r] = A[(size_t)(m0 + r) * lda + k0 + kl];
            Bs[kl][r] = B[(size_t)(n0 + r) * ldb + k0 + kl];
        }
        __syncthreads();
        #pragma unroll
        for (int k = 0; k < 16; ++k) {
            float4 av = *(const float4*)&As[k][ty * 4];
            float4 bv = *(const float4*)&Bs[k][tx * 4];
            float a4[4] = {av.x, av.y, av.z, av.w};
            float b4[4] = {bv.x, bv.y, bv.z, bv.w};
            #pragma unroll
            for (int i = 0; i < 4; ++i)
                #pragma unroll
                for (int j = 0; j < 4; ++j)
                    acc[i][j] = fmaf(a4[i], b4[j], acc[i][j]);
        }
        __syncthreads();
    }
    #pragma unroll
    for (int i = 0; i < 4; ++i) {
        int m = m0 + ty * 4 + i;
        #pragma unroll
        for (int j = 0; j < 4; ++j) {
            int n = n0 + tx * 4 + j;
            float v = acc[i][j] + bias[n];
            if (RELU) v = fmaxf(v, 0.f);
            C[(size_t)m * ldc + n] = v;
        }
    }
}

// ---------------------------------------------------------------------------
// Split-K GEMM, KSPLIT=4, partials to plain buffers (no atomics).
// ---------------------------------------------------------------------------
#define KSPLIT 4
__global__ __launch_bounds__(256) void gemm_ab_splitk(
    const float* __restrict__ A, const float* __restrict__ B,
    float* __restrict__ pA, float* __restrict__ pB,
    int M, int N, int K, int lda, int ldb, int ldc)
{
    __shared__ __align__(16) float As[16][68];
    __shared__ __align__(16) float Bs[16][68];
    const int tid = threadIdx.x;
    const int m0 = blockIdx.x * 64, n0 = blockIdx.y * 64;
    const int kchunk = K / KSPLIT;
    const int kbeg = blockIdx.z * kchunk, kend = kbeg + kchunk;
    const int tx = tid & 15, ty = tid >> 4;
    const int arow = tid & 63, akq = tid >> 6;
    const int bnq = tid & 15, bkk = tid >> 4;
    float acc[4][4] = {};

    float4 avn = *(const float4*)&A[(size_t)(m0 + arow) * lda + kbeg + akq * 4];
    float4 bvn = *(const float4*)&B[(size_t)(kbeg + bkk) * ldb + n0 + bnq * 4];

    for (int k0 = kbeg; k0 < kend; k0 += 16) {
        float4 av = avn, bv = bvn;
        if (k0 + 16 < kend) {
            avn = *(const float4*)&A[(size_t)(m0 + arow) * lda + k0 + 16 + akq * 4];
            bvn = *(const float4*)&B[(size_t)(k0 + 16 + bkk) * ldb + n0 + bnq * 4];
        }
        __syncthreads();
        As[akq * 4 + 0][arow] = av.x;
        As[akq * 4 + 1][arow] = av.y;
        As[akq * 4 + 2][arow] = av.z;
        As[akq * 4 + 3][arow] = av.w;
        *(float4*)&Bs[bkk][bnq * 4] = bv;
        __syncthreads();
        #pragma unroll
        for (int k = 0; k < 16; ++k) {
            float4 a4v = *(const float4*)&As[k][ty * 4];
            float4 b4v = *(const float4*)&Bs[k][tx * 4];
            float a4[4] = {a4v.x, a4v.y, a4v.z, a4v.w};
            float b4[4] = {b4v.x, b4v.y, b4v.z, b4v.w};
            #pragma unroll
            for (int i = 0; i < 4; ++i)
                #pragma unroll
                for (int j = 0; j < 4; ++j)
                    acc[i][j] = fmaf(a4[i], b4[j], acc[i][j]);
        }
    }
    float* Cp = (blockIdx.z < 2) ? (pA + (size_t)blockIdx.z * (ATT_H * N_ANTES))
                                 : (pB + (size_t)(blockIdx.z - 2) * (ATT_H * N_ANTES));
    #pragma unroll
    for (int i = 0; i < 4; ++i)
        #pragma unroll
        for (int j = 0; j < 4; ++j)
            Cp[(size_t)(m0 + ty * 4 + i) * ldc + n0 + tx * 4 + j] = acc[i][j];
}

__global__ __launch_bounds__(256) void k_reduce(
    const float* __restrict__ pA, const float* __restrict__ pB,
    float* __restrict__ preT)
{
    int gid = blockIdx.x * 256 + threadIdx.x;
    const int SZ = ATT_H * N_ANTES;
    preT[gid] = (pA[gid] + pA[gid + SZ]) + (pB[gid] + pB[gid + SZ]);
}

// ---------------------------------------------------------------------------
// rowsum[j] = sum_k w_ih[j, k]
// ---------------------------------------------------------------------------
__global__ __launch_bounds__(256) void k_rowsum(const float* __restrict__ w_ih,
                                                float* __restrict__ rowsum)
{
    __shared__ float red[256];
    const int j = blockIdx.x, tid = threadIdx.x;
    float s = 0.f;
    for (int i = tid; i < N_ANTES; i += 256) s += w_ih[(size_t)j * N_ANTES + i];
    red[tid] = s; __syncthreads();
    for (int off = 128; off > 0; off >>= 1) {
        if (tid < off) red[tid] += red[tid + off];
        __syncthreads();
    }
    if (tid == 0) rowsum[j] = red[0];
}

// ---------------------------------------------------------------------------
// wpkT[k*1024 + j] = w_hh[j*256 + k]
// ---------------------------------------------------------------------------
__global__ __launch_bounds__(256) void k_packT(const float* __restrict__ w_hh,
                                               float* __restrict__ wpkT)
{
    int gid = blockIdx.x * 256 + threadIdx.x;
    int j = gid >> 8;
    int k = gid & 255;
    wpkT[(size_t)k * 1024 + j] = w_hh[gid];
}

// ---------------------------------------------------------------------------
// WbT[k*256 + j] = att_w1[j*(N_TRAIN+ENC) + N_TRAIN + k]
// ---------------------------------------------------------------------------
__global__ __launch_bounds__(256) void k_wbT(const float* __restrict__ att_w1,
                                             float* __restrict__ WbT)
{
    int gid = blockIdx.x * 256 + threadIdx.x;
    int j = gid >> 8, k = gid & 255;
    WbT[(size_t)k * 256 + j] = att_w1[(size_t)j * (N_TRAIN + ENC) + N_TRAIN + k];
}

// ---------------------------------------------------------------------------
// LSTM step, high compute:LDS-read ratio. Grid 256 x 1024 (16 waves/CU).
// Thread (a = tid&255, kq = tid>>8) owns j-quad [4a,4a+4) x all 16 rows x
// k-quarter [kq*64, kq*64+64). Per k: one coalesced float4 w-load + 4
// broadcast ds_read_b128 of h -> 64 FMAs (16 FMA per b128, 4x the old ratio).
// k-partials summed through z_lds in 4 barrier-ordered rounds (deterministic).
// ---------------------------------------------------------------------------
#define LROWS 16
#define STEPR(r, hv) \
    { acc4[r].x = fmaf(w.x, (hv), acc4[r].x); \
      acc4[r].y = fmaf(w.y, (hv), acc4[r].y); \
      acc4[r].z = fmaf(w.z, (hv), acc4[r].z); \
      acc4[r].w = fmaf(w.w, (hv), acc4[r].w); }
#define KSTEP(w, kidx) \
    { const float4* hr = (const float4*)&h_lds[(kidx) * 16]; \
      float4 h0v = hr[0], h1v = hr[1], h2v = hr[2], h3v = hr[3]; \
      STEPR(0, h0v.x)  STEPR(1, h0v.y)  STEPR(2, h0v.z)  STEPR(3, h0v.w) \
      STEPR(4, h1v.x)  STEPR(5, h1v.y)  STEPR(6, h1v.z)  STEPR(7, h1v.w) \
      STEPR(8, h2v.x)  STEPR(9, h2v.y)  STEPR(10, h2v.z) STEPR(11, h2v.w) \
      STEPR(12, h3v.x) STEPR(13, h3v.y) STEPR(14, h3v.z) STEPR(15, h3v.w) }

__global__ __launch_bounds__(1024) void k_lstm(
    float* __restrict__ h, float* __restrict__ c,
    const float* __restrict__ wpkT, const float* __restrict__ rowsum,
    const float* __restrict__ b_ih, const float* __restrict__ b_hh,
    const float* __restrict__ S, const int* __restrict__ idx_buf, int t,
    float* __restrict__ e_acc_t)
{
    __shared__ __align__(16) float h_lds[256 * 16];     // [k][r], 16 KB
    __shared__ __align__(16) float z_lds[LROWS * 1024]; // [r][j], 64 KB
    __shared__ float red[1024];
    __shared__ float a_lds[LROWS];
    const int tid = threadIdx.x;
    const int n0 = blockIdx.x * LROWS;
    const int a  = tid & 255;       // j-quad: j in [4a, 4a+4)
    const int kq = tid >> 8;        // k-quarter
    const int jj = a, rq = kq;      // aliases for staging / gate phases

    if (tid < LROWS) {
        float av = 1.0f;
        if (t > 0) av = S[(size_t)(n0 + tid) * N_ANTES + idx_buf[t - 1]];
        a_lds[tid] = av;
    }
    // stage h tile -> h_lds[k][r]; thread covers k=jj, rows rq*4..rq*4+3
    #pragma unroll
    for (int i = 0; i < 4; ++i) {
        int r = rq * 4 + i;
        h_lds[jj * 16 + r] = h[(size_t)(n0 + r) * 256 + jj];
    }

    const float4 rs4 = *(const float4*)&rowsum[4 * a];
    const float4 bi4 = *(const float4*)&b_ih[4 * a];
    const float4 bh4 = *(const float4*)&b_hh[4 * a];
    const float4 bs4 = make_float4(bi4.x + bh4.x, bi4.y + bh4.y,
                                   bi4.z + bh4.z, bi4.w + bh4.w);
    __syncthreads();

    float4 acc4[LROWS];
    #pragma unroll
    for (int r = 0; r < LROWS; ++r) {
        if (kq == 0) {
            float av = a_lds[r];
            acc4[r] = make_float4(fmaf(av, rs4.x, bs4.x), fmaf(av, rs4.y, bs4.y),
                                  fmaf(av, rs4.z, bs4.z), fmaf(av, rs4.w, bs4.w));
        } else {
            acc4[r] = make_float4(0.f, 0.f, 0.f, 0.f);
        }
    }

    // K-loop over this thread's 64 k, 2-deep float4 w prefetch (wpkT padded)
    const float4* __restrict__ wp = (const float4*)wpkT;   // [k][256 quads]
    const int kb = kq * 64;
    float4 wbuf0 = wp[(size_t)(kb + 0) * 256 + a];
    float4 wbuf1 = wp[(size_t)(kb + 1) * 256 + a];
    for (int kk = 0; kk < 64; kk += 2) {
        {
            float4 w = wbuf0;
            wbuf0 = wp[(size_t)(kb + kk + 2) * 256 + a];   // pad rows safe
            KSTEP(w, kb + kk)
        }
        {
            float4 w = wbuf1;
            wbuf1 = wp[(size_t)(kb + kk + 3) * 256 + a];   // pad rows safe
            KSTEP(w, kb + kk + 1)
        }
    }

    // sum 4 k-partials into z_lds[r][j], rounds in ascending kq (deterministic)
    #pragma unroll
    for (int q = 0; q < 4; ++q) {
        if (kq == q) {
            #pragma unroll
            for (int r = 0; r < LROWS; ++r) {
                float4* dst = (float4*)&z_lds[r * 1024 + 4 * a];
                if (q == 0) {
                    *dst = acc4[r];
                } else {
                    float4 o = *dst;
                    o.x += acc4[r].x; o.y += acc4[r].y;
                    o.z += acc4[r].z; o.w += acc4[r].w;
                    *dst = o;
                }
            }
        }
        __syncthreads();
    }

    // gate update: thread (rq, jj) handles rows rq*4..rq*4+3, hidden unit jj
    float esum = 0.f;
    #pragma unroll
    for (int i = 0; i < 4; ++i) {
        int r = rq * 4 + i;
        float zi = z_lds[r * 1024 + jj];
        float zf = z_lds[r * 1024 + 256 + jj];
        float zg = z_lds[r * 1024 + 512 + jj];
        float zo = z_lds[r * 1024 + 768 + jj];
        size_t off = (size_t)(n0 + r) * 256 + jj;
        float cn = fsig(zf) * c[off] + fsig(zi) * ftanh(zg);
        float hn = fsig(zo) * ftanh(cn);
        c[off] = cn;
        h[off] = hn;
        esum += hn;
    }
    red[tid] = esum;
    __syncthreads();
    if (tid < 256) {
        float e = (red[tid] + red[tid + 256]) + (red[tid + 512] + red[tid + 768]);
        atomicAdd(&e_acc_t[tid], e);
    }
}

// ---------------------------------------------------------------------------
// Attention scores: 64 blocks, 32 cols each, 8 threads per col (R5-proven).
// ---------------------------------------------------------------------------
__global__ __launch_bounds__(256) void k_att1(
    const float* __restrict__ preT, const float* __restrict__ e_accum_t,
    const float* __restrict__ WbT, const float* __restrict__ att_b1,
    const float* __restrict__ att_w2, const float* __restrict__ att_b2,
    float* __restrict__ scores)
{
    __shared__ float e_lds[256];
    __shared__ float u[256];
    __shared__ float w2s[256];
    __shared__ float red[256];
    const int tid = threadIdx.x;
    e_lds[tid] = e_accum_t[tid] * (1.f / (float)N_TRAIN);
    w2s[tid] = att_w2[tid];
    __syncthreads();

    float uacc = att_b1[tid];
    for (int k = 0; k < 256; ++k)
        uacc = fmaf(e_lds[k], WbT[(size_t)k * 256 + tid], uacc);
    u[tid] = uacc;
    __syncthreads();

    const int pl = tid & 31, jq = tid >> 5;   // 8-way j split
    const int p = blockIdx.x * 32 + pl;
    float sc = 0.f;
    #pragma unroll 4
    for (int j = jq; j < 256; j += 8) {
        float v = preT[(size_t)j * N_ANTES + p] + u[j];
        sc = fmaf(fmaxf(v, 0.f), w2s[j], sc);
    }
    red[tid] = sc;
    __syncthreads();
    if (tid < 32) {
        float s = att_b2[0];
        #pragma unroll
        for (int q = 0; q < 8; ++q) s += red[tid + q * 32];
        scores[blockIdx.x * 32 + tid] = s;
    }
}

// ---------------------------------------------------------------------------
// log-softmax + argmax over 2048 scores (single block)
// ---------------------------------------------------------------------------
__global__ __launch_bounds__(256) void k_att2(
    const float* __restrict__ scores, float* __restrict__ out_t,
    int* __restrict__ idx_t)
{
    __shared__ float smax[256];
    __shared__ int   sidx[256];
    __shared__ float ssum[256];
    const int tid = threadIdx.x;

    float sv[8];
    #pragma unroll
    for (int i = 0; i < 8; ++i) sv[i] = scores[tid * 8 + i];

    float lmax = -INFINITY; int lidx = 0;
    #pragma unroll
    for (int i = 0; i < 8; ++i)
        if (sv[i] > lmax) { lmax = sv[i]; lidx = tid * 8 + i; }
    smax[tid] = lmax; sidx[tid] = lidx;
    __syncthreads();
    for (int off = 128; off > 0; off >>= 1) {
        if (tid < off) {
            float ov = smax[tid + off]; int oi = sidx[tid + off];
            if (ov > smax[tid] || (ov == smax[tid] && oi < sidx[tid])) {
                smax[tid] = ov; sidx[tid] = oi;
            }
        }
        __syncthreads();
    }
    const float gmax = smax[0];
    const int gidx = sidx[0];

    float lsum = 0.f;
    #pragma unroll
    for (int i = 0; i < 8; ++i) lsum += __expf(sv[i] - gmax);
    ssum[tid] = lsum;
    __syncthreads();
    for (int off = 128; off > 0; off >>= 1) {
        if (tid < off) ssum[tid] += ssum[tid + off];
        __syncthreads();
    }
    const float lse = gmax + logf(ssum[0]);

    #pragma unroll
    for (int i = 0; i < 8; ++i)
        out_t[tid * 8 + i] = sv[i] - lse;
    if (tid == 0) idx_t[0] = gidx;
}

// ---------------------------------------------------------------------------
extern "C" void kernel_launch(void* const* d_in, const int* in_sizes, int n_in,
                              void* d_out, int out_size, void* d_ws, size_t ws_size,
                              hipStream_t stream)
{
    (void)in_sizes; (void)n_in; (void)out_size; (void)ws_size;
    const float* context = (const float*)d_in[0];
    const float* S       = (const float*)d_in[1];
    const float* enc_w1  = (const float*)d_in[2];
    const float* enc_b1  = (const float*)d_in[3];
    const float* enc_w2  = (const float*)d_in[4];
    const float* enc_b2  = (const float*)d_in[5];
    const float* w_ih    = (const float*)d_in[6];
    const float* w_hh    = (const float*)d_in[7];
    const float* b_ih    = (const float*)d_in[8];
    const float* b_hh    = (const float*)d_in[9];
    const float* att_w1  = (const float*)d_in[10];
    const float* att_b1  = (const float*)d_in[11];
    const float* att_w2  = (const float*)d_in[12];
    const float* att_b2  = (const float*)d_in[13];
    float* out = (float*)d_out;
    float* ws  = (float*)d_ws;

    // ws layout (float offsets)
    float* h      = ws;                        // 1,048,576
    float* c      = ws + 1048576;              // 1,048,576
    float* pAbuf  = ws + 2097152;              // 1,048,576 (hid1 aliases slice 0)
    float* preT   = ws + 3145728;              // 524,288 (j-major [j][p])
    float* pBbuf  = ws + 3670016;              // 1,048,576
    float* wpkT   = ws + 4718592;              // (256+4)*1024 = 266,240
    float* rowsum = ws + 4984832;              // 1,024
    float* e_acc  = ws + 4985856;              // 4,096
    float* scores = ws + 4989952;              // 2,048
    float* WbT    = ws + 4992000;              // 65,536
    int*   idxbuf = (int*)(ws + 5057536);      // 16

    hipMemsetAsync(c, 0, (size_t)N_TRAIN * ENC * sizeof(float), stream);
    hipMemsetAsync(e_acc, 0, (size_t)MAX_LEN * ENC * sizeof(float), stream);

    k_rowsum<<<1024, 256, 0, stream>>>(w_ih, rowsum);
    k_packT<<<1024, 256, 0, stream>>>(w_hh, wpkT);
    k_wbT<<<256, 256, 0, stream>>>(att_w1, WbT);

    // encoder: hid1 = relu(context @ enc_w1.T + b1); h = hid1 @ enc_w2.T + b2
    float* hid1 = pAbuf;
    dim3 g1(N_TRAIN / 64, N_HID / 64);
    gemm_abT<true><<<g1, 256, 0, stream>>>(context, enc_w1, enc_b1, hid1,
                                           N_TRAIN, N_HID, N_FEAT, N_FEAT, N_FEAT, N_HID);
    dim3 g2(N_TRAIN / 64, ENC / 64);
    gemm_abT<false><<<g2, 256, 0, stream>>>(hid1, enc_w2, enc_b2, h,
                                            N_TRAIN, ENC, N_HID, N_HID, N_HID, ENC);
    // preT = Wa @ S via split-K=4 partials (pAbuf reused after gemm #2)
    dim3 g3(ATT_H / 64, N_ANTES / 64, KSPLIT);
    gemm_ab_splitk<<<g3, 256, 0, stream>>>(att_w1, S, pAbuf, pBbuf,
                                           ATT_H, N_ANTES, N_TRAIN,
                                           N_TRAIN + ENC, N_ANTES, N_ANTES);
    k_reduce<<<(ATT_H * N_ANTES) / 256, 256, 0, stream>>>(pAbuf, pBbuf, preT);

    for (int t = 0; t < MAX_LEN; ++t) {
        k_lstm<<<N_TRAIN / LROWS, 1024, 0, stream>>>(h, c, wpkT, rowsum, b_ih,
                                                     b_hh, S, idxbuf, t,
                                                     e_acc + t * 256);
        k_att1<<<N_ANTES / 32, 256, 0, stream>>>(preT, e_acc + t * 256, WbT,
                                                 att_b1, att_w2, att_b2, scores);
        k_att2<<<1, 256, 0, stream>>>(scores, out + t * N_ANTES, idxbuf + t);
    }
}